// Round 8
// baseline (397.332 us; speedup 1.0000x reference)
//
#include <hip/hip_runtime.h>

// SKANLinear: y[b,o] = sum_{i=0}^{IN} weight[o,i] * sin(w[o,i] * x_ext[b,i])
// x_ext[b,IN] = 1.0. B=2048, IN=256, OUT=256. f32.
//
// R8: R7 counters: kernel 42.7us, Occupancy 31% (grid 1024 = 4 blk/CU caps
// waves at 50%), VALUBusy 59%, LDS conflicts 4% (ignore), hbm 3%.
// => latency-gapped, occupancy-capped. Fix: wave = ONE o (uniform), grid =
// 2048 blocks = 8 blk/CU = 32 waves/CU (100% cap). v_sin math (fastest
// measured: R4/R5 kernel ~32us at 2.5 waves/SIMD). Double-buffered LDS
// chunk -> ONE barrier per chunk; barrier drain overlaps across 8 blocks/CU.
// Per element: v_mul + v_sin(trans) + v_fma, weights via scalar pipe,
// per-lane full (b,o) sums, no shuffles.

#define IN_DIM 256
#define OUT_DIM 256
#define LDW 257
#define CH 32             // i-chunk width
#define INV_2PI 0.15915494309189535f

__global__ __launch_bounds__(256, 8)
void skan_kernel(const float* __restrict__ x,      // [2048][256]
                 const float* __restrict__ weight, // [256][257]
                 const float* __restrict__ wfreq,  // [256][257]
                 float* __restrict__ y)            // [2048][256]
{
    __shared__ float4 lxA[64 * 8];   // chunk double-buffer, 8 KB each
    __shared__ float4 lxB[64 * 8];

    const int t  = threadIdx.x;
    const int l  = t & 63;                                   // lane = local b
    const int wv = __builtin_amdgcn_readfirstlane(t >> 6);   // wave id, uniform

    const int o  = (blockIdx.x & 63) * 4 + wv;               // one o per wave
    const int b0 = (blockIdx.x >> 6) * 64;

    const float* __restrict__ wr = wfreq  + o * LDW;  // uniform -> s_load
    const float* __restrict__ gr = weight + o * LDW;

    // bias column (i=256, x_ext=1): each lane owns a full (b,o) sum.
    float acc = gr[IN_DIM] * __builtin_amdgcn_sinf(wr[IN_DIM] * INV_2PI);

    // stage chunk ic into buf: 512 float4 by 256 threads (2 each), coalesced
    // global reads, XOR-swizzled 16B LDS writes, pre-scaled by 1/(2pi).
    auto stage = [&](float4* buf, int ic) {
#pragma unroll
        for (int k = 0; k < 2; ++k) {
            const int f  = t + k * 256;
            const int r  = f >> 3;       // local b row
            const int c4 = f & 7;        // float4 block within chunk
            float4 v = *(const float4*)(x + (b0 + r) * IN_DIM + ic * CH + c4 * 4);
            v.x *= INV_2PI; v.y *= INV_2PI; v.z *= INV_2PI; v.w *= INV_2PI;
            buf[r * 8 + (c4 ^ (r & 7))] = v;
        }
    };

    stage(lxA, 0);
    __syncthreads();

    for (int ic = 0; ic < 8; ++ic) {
        float4* cur = (ic & 1) ? lxB : lxA;
        float4* nxt = (ic & 1) ? lxA : lxB;

        if (ic < 7) stage(nxt, ic + 1);

        // readback my b-row: 8 x ds_read_b128 (swizzled)
        float xs[CH];
#pragma unroll
        for (int c4 = 0; c4 < 8; ++c4) {
            const float4 v = cur[l * 8 + (c4 ^ (l & 7))];
            xs[c4 * 4 + 0] = v.x; xs[c4 * 4 + 1] = v.y;
            xs[c4 * 4 + 2] = v.z; xs[c4 * 4 + 3] = v.w;
        }

        // one barrier per chunk:
        //  - guarantees this iter's stage(nxt) is visible before next iter
        //    reads it, and all readbacks of cur are done before iter ic+1
        //    overwrites it. Compute below needs no barrier.
        __syncthreads();

        // inner: v_mul(s,v) + v_sin + v_fma(s,v,v); w/g via scalar pipe
        const int ib = ic * CH;
#pragma unroll
        for (int j = 0; j < CH; ++j) {
            acc = fmaf(gr[ib + j],
                       __builtin_amdgcn_sinf(wr[ib + j] * xs[j]), acc);
        }
    }

    y[(b0 + l) * OUT_DIM + o] = acc;
}

extern "C" void kernel_launch(void* const* d_in, const int* in_sizes, int n_in,
                              void* d_out, int out_size, void* d_ws, size_t ws_size,
                              hipStream_t stream) {
    const float* x      = (const float*)d_in[0];
    const float* weight = (const float*)d_in[1];
    const float* wfreq  = (const float*)d_in[2];
    float* y            = (float*)d_out;

    const int B = in_sizes[0] / IN_DIM;            // 2048
    const int grid = (B / 64) * (OUT_DIM / 4);     // 32 * 64 = 2048

    skan_kernel<<<grid, 256, 0, stream>>>(x, weight, wfreq, y);
}

// Round 9
// 394.246 us; speedup vs baseline: 1.0078x; 1.0078x over previous
//
#include <hip/hip_runtime.h>

// SKANLinear: y[b,o] = sum_{i=0}^{IN} weight[o,i] * sin(w[o,i] * x_ext[b,i])
// x_ext[b,IN] = 1.0. B=2048, IN=256, OUT=256. f32.
//
// R9 = R8 structure with the spill fixed. R8's launch_bounds(256,8) gave a
// 64-VGPR budget -> xs[32] spilled to scratch (WRITE_SIZE 715MB, 347us).
// (256,6) gives ~85 VGPRs: xs[32] + staging fits, occupancy cap 75%
// (24 waves/CU) vs R7's measured 31%.
//  - wave = ONE o (uniform): weights via scalar pipe
//  - x chunk (64b x 32i) double-buffered in XOR-swizzled LDS float4,
//    pre-scaled by 1/(2pi); ONE barrier per chunk
//  - inner: v_mul(s,v) + v_sin(trans) + v_fma(s,v,v); per-lane full sums,
//    no shuffles
// Discriminator: if kernel stays >=28us at >=60% occupancy, v_sin is
// ~37cyc/wave throughput-limited -> next: hybrid trans+VALU split.

#define IN_DIM 256
#define OUT_DIM 256
#define LDW 257
#define CH 32             // i-chunk width
#define INV_2PI 0.15915494309189535f

__global__ __launch_bounds__(256, 6)
void skan_kernel(const float* __restrict__ x,      // [2048][256]
                 const float* __restrict__ weight, // [256][257]
                 const float* __restrict__ wfreq,  // [256][257]
                 float* __restrict__ y)            // [2048][256]
{
    __shared__ float4 lxA[64 * 8];   // chunk double-buffer, 8 KB each
    __shared__ float4 lxB[64 * 8];

    const int t  = threadIdx.x;
    const int l  = t & 63;                                   // lane = local b
    const int wv = __builtin_amdgcn_readfirstlane(t >> 6);   // wave id, uniform

    const int o  = (blockIdx.x & 63) * 4 + wv;               // one o per wave
    const int b0 = (blockIdx.x >> 6) * 64;

    const float* __restrict__ wr = wfreq  + o * LDW;  // uniform -> s_load
    const float* __restrict__ gr = weight + o * LDW;

    // bias column (i=256, x_ext=1): each lane owns a full (b,o) sum.
    float acc = gr[IN_DIM] * __builtin_amdgcn_sinf(wr[IN_DIM] * INV_2PI);

    // stage chunk ic into buf: 512 float4 by 256 threads (2 each), coalesced
    // global reads, XOR-swizzled 16B LDS writes, pre-scaled by 1/(2pi).
    auto stage = [&](float4* buf, int ic) {
#pragma unroll
        for (int k = 0; k < 2; ++k) {
            const int f  = t + k * 256;
            const int r  = f >> 3;       // local b row
            const int c4 = f & 7;        // float4 block within chunk
            float4 v = *(const float4*)(x + (b0 + r) * IN_DIM + ic * CH + c4 * 4);
            v.x *= INV_2PI; v.y *= INV_2PI; v.z *= INV_2PI; v.w *= INV_2PI;
            buf[r * 8 + (c4 ^ (r & 7))] = v;
        }
    };

    stage(lxA, 0);
    __syncthreads();

    for (int ic = 0; ic < 8; ++ic) {
        float4* cur = (ic & 1) ? lxB : lxA;
        float4* nxt = (ic & 1) ? lxA : lxB;

        if (ic < 7) stage(nxt, ic + 1);

        // readback my b-row: 8 x ds_read_b128 (swizzled) into registers
        float xs[CH];
#pragma unroll
        for (int c4 = 0; c4 < 8; ++c4) {
            const float4 v = cur[l * 8 + (c4 ^ (l & 7))];
            xs[c4 * 4 + 0] = v.x; xs[c4 * 4 + 1] = v.y;
            xs[c4 * 4 + 2] = v.z; xs[c4 * 4 + 3] = v.w;
        }

        // one barrier per chunk: readback(cur) precedes it; next iter's
        // overwrite of cur follows it. Compute below needs no barrier.
        __syncthreads();

        // inner: v_mul(s,v) + v_sin + v_fma(s,v,v); w/g via scalar pipe
        const int ib = ic * CH;
#pragma unroll
        for (int j = 0; j < CH; ++j) {
            acc = fmaf(gr[ib + j],
                       __builtin_amdgcn_sinf(wr[ib + j] * xs[j]), acc);
        }
    }

    y[(b0 + l) * OUT_DIM + o] = acc;
}

extern "C" void kernel_launch(void* const* d_in, const int* in_sizes, int n_in,
                              void* d_out, int out_size, void* d_ws, size_t ws_size,
                              hipStream_t stream) {
    const float* x      = (const float*)d_in[0];
    const float* weight = (const float*)d_in[1];
    const float* wfreq  = (const float*)d_in[2];
    float* y            = (float*)d_out;

    const int B = in_sizes[0] / IN_DIM;            // 2048
    const int grid = (B / 64) * (OUT_DIM / 4);     // 32 * 64 = 2048

    skan_kernel<<<grid, 256, 0, stream>>>(x, weight, wfreq, y);
}